// Round 1
// baseline (432.726 us; speedup 1.0000x reference)
//
#include <hip/hip_runtime.h>
#include <stdint.h>

#define TILE 128
#define BK 32
#define LDST 40   // 32 + 8 pad: keeps ds_read_b128 16B-aligned (80B row stride), <=2-way bank alias

typedef __attribute__((ext_vector_type(8))) short short8;
typedef __attribute__((ext_vector_type(4))) float f32x4;

static __device__ __forceinline__ unsigned short f2bf(float f) {
    union { float f; uint32_t u; } v; v.f = f;
    uint32_t u = v.u;
    u += 0x7fffu + ((u >> 16) & 1u);   // round-to-nearest-even
    return (unsigned short)(u >> 16);
}

// xp = x @ W + b   (M=65536, K=512, N=512), bf16 MFMA, fp32 in/out
__global__ __launch_bounds__(256, 2)
void gemm_bias_kernel(const float* __restrict__ X, const float* __restrict__ W,
                      const float* __restrict__ bias, float* __restrict__ out)
{
    __shared__ unsigned short As[TILE * LDST];
    __shared__ unsigned short Bs[TILE * LDST];

    const int tid = threadIdx.x;
    const int rowBase = blockIdx.x * TILE;
    const int colBase = blockIdx.y * TILE;

    const int wave  = tid >> 6;
    const int lane  = tid & 63;
    const int m16   = lane & 15;
    const int quad  = lane >> 4;
    const int waveM = wave & 1;    // 2x2 wave grid, each wave does 64x64
    const int waveN = wave >> 1;

    f32x4 acc[4][4] = {};

    const int arow  = tid >> 3;    // 0..31 (A staging row within pass)
    const int acol4 = tid & 7;     // 0..7  (float4 col)
    const int bk    = tid >> 5;    // 0..7  (B staging k within pass)
    const int bn4   = tid & 31;    // 0..31 (float4 col in n)

    for (int kt = 0; kt < 512; kt += BK) {
        // ---- stage A tile: 128 x 32, row-major [m][k] in LDS ----
        #pragma unroll
        for (int p = 0; p < 4; ++p) {
            int r = p * 32 + arow;
            float4 v = *(const float4*)(X + (size_t)(rowBase + r) * 512 + kt + acol4 * 4);
            ushort4 us;
            us.x = f2bf(v.x); us.y = f2bf(v.y); us.z = f2bf(v.z); us.w = f2bf(v.w);
            *(ushort4*)(&As[r * LDST + acol4 * 4]) = us;
        }
        // ---- stage B tile: 32 x 128, stored transposed [n][k] in LDS ----
        #pragma unroll
        for (int p = 0; p < 4; ++p) {
            int k = p * 8 + bk;
            float4 v = *(const float4*)(W + (size_t)(kt + k) * 512 + colBase + bn4 * 4);
            Bs[(bn4 * 4 + 0) * LDST + k] = f2bf(v.x);
            Bs[(bn4 * 4 + 1) * LDST + k] = f2bf(v.y);
            Bs[(bn4 * 4 + 2) * LDST + k] = f2bf(v.z);
            Bs[(bn4 * 4 + 3) * LDST + k] = f2bf(v.w);
        }
        __syncthreads();

        // ---- fragments + MFMA ----
        short8 a_frag[4], b_frag[4];
        #pragma unroll
        for (int mi = 0; mi < 4; ++mi)
            a_frag[mi] = *(const short8*)&As[(waveM * 64 + mi * 16 + m16) * LDST + quad * 8];
        #pragma unroll
        for (int ni = 0; ni < 4; ++ni)
            b_frag[ni] = *(const short8*)&Bs[(waveN * 64 + ni * 16 + m16) * LDST + quad * 8];

        #pragma unroll
        for (int mi = 0; mi < 4; ++mi)
            #pragma unroll
            for (int ni = 0; ni < 4; ++ni)
                acc[mi][ni] = __builtin_amdgcn_mfma_f32_16x16x32_bf16(
                    a_frag[mi], b_frag[ni], acc[mi][ni], 0, 0, 0);
        __syncthreads();
    }

    // ---- epilogue: add bias, store fp32 ----
    // C/D layout (m89-verified): col = lane&15, row = quad*4 + reg
    #pragma unroll
    for (int ni = 0; ni < 4; ++ni) {
        int col = colBase + waveN * 64 + ni * 16 + m16;
        float bv = bias[col];
        #pragma unroll
        for (int mi = 0; mi < 4; ++mi) {
            int row0 = rowBase + waveM * 64 + mi * 16 + quad * 4;
            #pragma unroll
            for (int r = 0; r < 4; ++r)
                out[(size_t)(row0 + r) * 512 + col] = acc[mi][ni][r] + bv;
        }
    }
}

// In-place scan over t: h_t = relu(xp_t + u*h_{t-1}), h_0 = 1
// One thread per (b, r) chain; 16-deep double-buffered t-prefetch for MLP.
#define UNR 16
__global__ __launch_bounds__(64)
void scan_kernel(float* __restrict__ out, const float* __restrict__ u)
{
    const int gid = blockIdx.x * 64 + threadIdx.x;  // 0..32767
    const int b = gid >> 9;
    const int r = gid & 511;
    const float ur = u[r];
    float* p = out + (size_t)b * 1024 * 512 + r;

    float h = 1.0f;
    float cur[UNR], nxt[UNR];
    #pragma unroll
    for (int j = 0; j < UNR; ++j) cur[j] = p[(size_t)j * 512];

    for (int t0 = 0; t0 < 1024; t0 += UNR) {
        const bool more = (t0 + UNR) < 1024;
        const float* pn = p + (size_t)(t0 + UNR) * 512;
        if (more) {
            #pragma unroll
            for (int j = 0; j < UNR; ++j) nxt[j] = pn[(size_t)j * 512];
        }
        #pragma unroll
        for (int j = 0; j < UNR; ++j) {
            h = fmaxf(fmaf(ur, h, cur[j]), 0.0f);
            p[(size_t)(t0 + j) * 512] = h;
        }
        #pragma unroll
        for (int j = 0; j < UNR; ++j) cur[j] = nxt[j];
    }
}

extern "C" void kernel_launch(void* const* d_in, const int* in_sizes, int n_in,
                              void* d_out, int out_size, void* d_ws, size_t ws_size,
                              hipStream_t stream) {
    const float* x = (const float*)d_in[0];   // [64,1024,512]
    const float* W = (const float*)d_in[1];   // [512,512]
    const float* u = (const float*)d_in[2];   // [512]
    const float* b = (const float*)d_in[3];   // [512]
    float* out = (float*)d_out;               // [64,1024,512]

    dim3 grid(65536 / TILE, 512 / TILE);      // (512, 4)
    gemm_bias_kernel<<<grid, 256, 0, stream>>>(x, W, b, out);
    scan_kernel<<<512, 64, 0, stream>>>(out, u);
}

// Round 2
// 323.503 us; speedup vs baseline: 1.3376x; 1.3376x over previous
//
#include <hip/hip_runtime.h>
#include <hip/hip_fp16.h>
#include <stdint.h>

#define TILE 128
#define BK 32
#define LDST 40   // 32 + 8 pad: 80B row stride keeps 16B alignment, <=2-way bank alias

typedef __attribute__((ext_vector_type(8))) short short8;
typedef __attribute__((ext_vector_type(8))) unsigned short ushort8;
typedef __attribute__((ext_vector_type(4))) float f32x4;

static __device__ __forceinline__ unsigned short f2bf(float f) {
    union { float f; uint32_t u; } v; v.f = f;
    uint32_t u = v.u;
    u += 0x7fffu + ((u >> 16) & 1u);   // RNE
    return (unsigned short)(u >> 16);
}

// ---------------- W transpose+convert: Wt[n][k] bf16 from W[k][n] fp32 ----------------
__global__ __launch_bounds__(256)
void wt_kernel(const float* __restrict__ W, unsigned short* __restrict__ Wt)
{
    __shared__ float s[32][33];
    const int tx = threadIdx.x;          // 0..31
    const int ty = threadIdx.y;          // 0..7
    const int kBase = blockIdx.x * 32;
    const int nBase = blockIdx.y * 32;
    #pragma unroll
    for (int j = 0; j < 4; ++j)
        s[ty + 8 * j][tx] = W[(size_t)(kBase + ty + 8 * j) * 512 + nBase + tx];
    __syncthreads();
    #pragma unroll
    for (int j = 0; j < 4; ++j)
        Wt[(size_t)(nBase + ty + 8 * j) * 512 + kBase + tx] = f2bf(s[tx][ty + 8 * j]);
}

// ---------------- xp = x @ W + b  (M=65536, K=512, N=512) ----------------
// A from fp32 X (convert on stage), B from pre-transposed bf16 Wt[n][k].
template <bool F16OUT>
__global__ __launch_bounds__(256, 2)
void gemm_bias_kernel(const float* __restrict__ X, const unsigned short* __restrict__ Wt,
                      const float* __restrict__ bias,
                      float* __restrict__ out32, __half* __restrict__ out16)
{
    __shared__ unsigned short As[TILE * LDST];
    __shared__ unsigned short Bs[TILE * LDST];

    const int tid = threadIdx.x;
    const int colBase = blockIdx.x * TILE;   // ntile fast -> L2 sharing of X stripes
    const int rowBase = blockIdx.y * TILE;

    const int wave  = tid >> 6;
    const int lane  = tid & 63;
    const int m16   = lane & 15;
    const int quad  = lane >> 4;
    const int waveM = wave & 1;
    const int waveN = wave >> 1;

    f32x4 acc[4][4] = {};

    const int srow = tid >> 2;   // 0..63
    const int sc4  = tid & 3;    // 0..3 (k-chunk of 8)

    for (int kt = 0; kt < 512; kt += BK) {
        // ---- stage A: 128 x 32, [m][k], convert fp32->bf16, ushort8 writes ----
        #pragma unroll
        for (int p = 0; p < 2; ++p) {
            int r = p * 64 + srow;
            const float* src = X + (size_t)(rowBase + r) * 512 + kt + sc4 * 8;
            float4 v0 = *(const float4*)(src);
            float4 v1 = *(const float4*)(src + 4);
            ushort8 us;
            us[0] = f2bf(v0.x); us[1] = f2bf(v0.y); us[2] = f2bf(v0.z); us[3] = f2bf(v0.w);
            us[4] = f2bf(v1.x); us[5] = f2bf(v1.y); us[6] = f2bf(v1.z); us[7] = f2bf(v1.w);
            *(ushort8*)(&As[r * LDST + sc4 * 8]) = us;
        }
        // ---- stage B: 128 x 32, [n][k] straight copy from Wt, ushort8 ----
        #pragma unroll
        for (int p = 0; p < 2; ++p) {
            int n = p * 64 + srow;
            ushort8 v = *(const ushort8*)(Wt + (size_t)(colBase + n) * 512 + kt + sc4 * 8);
            *(ushort8*)(&Bs[n * LDST + sc4 * 8]) = v;
        }
        __syncthreads();

        short8 a_frag[4], b_frag[4];
        #pragma unroll
        for (int mi = 0; mi < 4; ++mi)
            a_frag[mi] = *(const short8*)&As[(waveM * 64 + mi * 16 + m16) * LDST + quad * 8];
        #pragma unroll
        for (int ni = 0; ni < 4; ++ni)
            b_frag[ni] = *(const short8*)&Bs[(waveN * 64 + ni * 16 + m16) * LDST + quad * 8];

        #pragma unroll
        for (int mi = 0; mi < 4; ++mi)
            #pragma unroll
            for (int ni = 0; ni < 4; ++ni)
                acc[mi][ni] = __builtin_amdgcn_mfma_f32_16x16x32_bf16(
                    a_frag[mi], b_frag[ni], acc[mi][ni], 0, 0, 0);
        __syncthreads();
    }

    // ---- epilogue: + bias; C/D layout (m89): col=lane&15, row=quad*4+reg ----
    #pragma unroll
    for (int ni = 0; ni < 4; ++ni) {
        int col = colBase + waveN * 64 + ni * 16 + m16;
        float bv = bias[col];
        #pragma unroll
        for (int mi = 0; mi < 4; ++mi) {
            int row0 = rowBase + waveM * 64 + mi * 16 + quad * 4;
            #pragma unroll
            for (int r = 0; r < 4; ++r) {
                float v = acc[mi][ni][r] + bv;
                if (F16OUT) out16[(size_t)(row0 + r) * 512 + col] = __float2half_rn(v);
                else        out32[(size_t)(row0 + r) * 512 + col] = v;
            }
        }
    }
}

// ---------------- scan: h_t = relu(xp_t + u*h_{t-1}), h_0 = 1 ----------------
#define UNR 32

// fp16-xp variant (xp in ws, h fp32 to out)
__global__ __launch_bounds__(64)
void scan_f16_kernel(const __half* __restrict__ xp, float* __restrict__ out,
                     const float* __restrict__ u)
{
    const int gid = blockIdx.x * 64 + threadIdx.x;  // 0..32767
    const int b = gid >> 9;
    const int r = gid & 511;
    const float ur = u[r];
    const unsigned short* p16 = (const unsigned short*)xp + (size_t)b * 1024 * 512 + r;
    float* po = out + (size_t)b * 1024 * 512 + r;

    float h = 1.0f;
    unsigned short cur[UNR], nxt[UNR];
    #pragma unroll
    for (int j = 0; j < UNR; ++j) cur[j] = p16[(size_t)j * 512];

    for (int t0 = 0; t0 < 1024; t0 += UNR) {
        const bool more = (t0 + UNR) < 1024;
        const unsigned short* pn = p16 + (size_t)(t0 + UNR) * 512;
        if (more) {
            #pragma unroll
            for (int j = 0; j < UNR; ++j) nxt[j] = pn[(size_t)j * 512];
        }
        #pragma unroll
        for (int j = 0; j < UNR; ++j) {
            float xv = __half2float(__ushort_as_half(cur[j]));
            h = fmaxf(fmaf(ur, h, xv), 0.0f);
            po[(size_t)(t0 + j) * 512] = h;
        }
        #pragma unroll
        for (int j = 0; j < UNR; ++j) cur[j] = nxt[j];
    }
}

// fp32 in-place fallback
__global__ __launch_bounds__(64)
void scan_f32_kernel(float* __restrict__ out, const float* __restrict__ u)
{
    const int gid = blockIdx.x * 64 + threadIdx.x;
    const int b = gid >> 9;
    const int r = gid & 511;
    const float ur = u[r];
    float* p = out + (size_t)b * 1024 * 512 + r;

    float h = 1.0f;
    float cur[UNR], nxt[UNR];
    #pragma unroll
    for (int j = 0; j < UNR; ++j) cur[j] = p[(size_t)j * 512];

    for (int t0 = 0; t0 < 1024; t0 += UNR) {
        const bool more = (t0 + UNR) < 1024;
        const float* pn = p + (size_t)(t0 + UNR) * 512;
        if (more) {
            #pragma unroll
            for (int j = 0; j < UNR; ++j) nxt[j] = pn[(size_t)j * 512];
        }
        #pragma unroll
        for (int j = 0; j < UNR; ++j) {
            h = fmaxf(fmaf(ur, h, cur[j]), 0.0f);
            p[(size_t)(t0 + j) * 512] = h;
        }
        #pragma unroll
        for (int j = 0; j < UNR; ++j) cur[j] = nxt[j];
    }
}

extern "C" void kernel_launch(void* const* d_in, const int* in_sizes, int n_in,
                              void* d_out, int out_size, void* d_ws, size_t ws_size,
                              hipStream_t stream) {
    const float* x = (const float*)d_in[0];   // [64,1024,512]
    const float* W = (const float*)d_in[1];   // [512,512]
    const float* u = (const float*)d_in[2];   // [512]
    const float* b = (const float*)d_in[3];   // [512]
    float* out = (float*)d_out;               // [64,1024,512] fp32

    const size_t WT_BYTES = (size_t)512 * 512 * 2;              // 512 KB bf16 Wt
    const size_t XP_BYTES = (size_t)64 * 1024 * 512 * 2;        // 64 MB fp16 xp
    unsigned short* Wt = (unsigned short*)d_ws;
    __half* xp16 = (__half*)((char*)d_ws + WT_BYTES);
    const bool f16path = ws_size >= WT_BYTES + XP_BYTES;        // deterministic -> graph-safe

    dim3 tgrid(16, 16), tblk(32, 8);
    wt_kernel<<<tgrid, tblk, 0, stream>>>(W, Wt);

    dim3 grid(512 / TILE, 65536 / TILE);      // (4 ntiles fast, 512 mtiles)
    if (f16path) {
        gemm_bias_kernel<true><<<grid, 256, 0, stream>>>(x, Wt, b, nullptr, xp16);
        scan_f16_kernel<<<512, 64, 0, stream>>>(xp16, out, u);
    } else {
        gemm_bias_kernel<false><<<grid, 256, 0, stream>>>(x, Wt, b, out, nullptr);
        scan_f32_kernel<<<512, 64, 0, stream>>>(out, u);
    }
}